// Round 14
// baseline (51.239 us; speedup 1.0000x reference)
//
#include <hip/hip_runtime.h>
#include <math.h>

#define IMG 224
#define NPIX 50176
#define BATCH 64
#define EDIM 256

typedef _Float16 f16;
typedef __attribute__((ext_vector_type(8))) _Float16 f16x8;
typedef __attribute__((ext_vector_type(4))) _Float16 f16x4;
typedef __attribute__((ext_vector_type(4))) float f32x4;
typedef unsigned int u32;

// gemmA: 32x256 tile, 448 blocks, A=gray(x) reg-staged 2-deep prefetch,
//   B=B1 Chebyshev-recurrence in LDS. HBM-FLOOR ~6.5us (R11 ledger) — frozen.
//   Tail: fills one W2h row per block; block 0 zeroes stats.
// gemmB: R14 ABLATION — identical tile/staging/epilogue to R12 but the
//   K-loop is the R2-proven compiler-scheduled core: single-buffer,
//   plain __syncthreads(), NO inline asm. (Every manual-vmcnt variant
//   R5-R13 sat at 38-46us; R2's plain-sync core implied >=3x better/FLOP.)
// mlp: R9-proven paired version.

#define GLD16(gp, lp)                                                          \
  __builtin_amdgcn_global_load_lds(                                            \
      (const __attribute__((address_space(1))) u32*)(gp),                      \
      (__attribute__((address_space(3))) u32*)(lp), 16, 0, 0)

// ---- gemmA: Y = gray(x) * B1^T -> fp16 B2t; fills W2h; zeroes stats -------
__global__ __launch_bounds__(256) void gemmA_kernel(const float* __restrict__ x,
                                                    f16* __restrict__ B2t,
                                                    f16* __restrict__ W2h,
                                                    u32* __restrict__ statsz) {
  __shared__ float T[224];
  __shared__ f16 As[2][32][64];     // 8 KB
  __shared__ f16 Bs[2][256][64];    // 64 KB
  int m0 = blockIdx.x * 32;
  int tid = threadIdx.x;
  int lane = tid & 63, wid = tid >> 6;

  if (blockIdx.x == 0) {            // stats (2176 f32)
#pragma unroll
    for (int i = 0; i < 9; ++i) {
      int idx = i * 256 + tid;
      if (idx < 2176) statsz[idx] = 0u;
    }
  }

  int arow = tid >> 3;
  int aseg = tid & 7;
  int am = m0 + arow;
  int ab = am / 224, ah = am - ab * 224;
  const float* px = x + (size_t)ab * 3 * NPIX + ah * IMG;
  int s0 = aseg ^ (arow & 7);       // swizzled 16B slot (involution)

  f32x4 xlA[3][2], xlB[3][2];
  f32x4 acc[2][4];
#pragma unroll
  for (int i = 0; i < 2; ++i)
#pragma unroll
    for (int j = 0; j < 4; ++j) acc[i][j] = (f32x4){0.f, 0.f, 0.f, 0.f};

  auto issueA = [&](f32x4 (&xl)[3][2], int t) {
    int kb = t * 64 + aseg * 8;
    if (kb < 224) {
#pragma unroll
      for (int c = 0; c < 3; ++c) {
        xl[c][0] = *(const f32x4*)(px + c * NPIX + kb);
        xl[c][1] = *(const f32x4*)(px + c * NPIX + kb + 4);
      }
    }
  };
  auto writeA = [&](f32x4 (&xl)[3][2], int t, int bufi) {
    int kb = t * 64 + aseg * 8;
    f16x8 h0;
    if (kb < 224) {
#pragma unroll
      for (int j = 0; j < 8; ++j) {
        int q = j >> 2, r = j & 3;
        h0[j] = (f16)((xl[0][q][r] + xl[1][q][r] + xl[2][q][r]) * (1.0f / 3.0f));
      }
    } else {
#pragma unroll
      for (int j = 0; j < 8; ++j) h0[j] = (f16)0.f;
    }
    *(f16x8*)&As[bufi][arow][s0 * 8] = h0;
  };
  auto computeB = [&](int bufi, int t) {
    int row = tid;
    int v = (row < 113) ? row : row - 113;
    u32 off = (row < 113) ? 0u : 56u;
    u32 idx0 = ((u32)(t * 64) * (u32)v + off) % 224u;
    u32 idxm = (idx0 >= (u32)v) ? idx0 - (u32)v : idx0 + 224u - (u32)v;
    float cur = T[idx0];
    float prev = T[idxm];
    float k2c = 2.0f * T[v];
#pragma unroll
    for (int g = 0; g < 8; ++g) {
      f16x8 hv;
#pragma unroll
      for (int j = 0; j < 8; ++j) {
        hv[j] = (f16)cur;
        float nxt = __builtin_fmaf(k2c, cur, -prev);
        prev = cur; cur = nxt;
      }
      *(f16x8*)&Bs[bufi][row][(g ^ (row & 7)) * 8] = hv;
    }
  };
  auto mfmaStep = [&](int bufi) {
#pragma unroll
    for (int kk = 0; kk < 2; ++kk) {
      f16x8 af[2], bfr[4];
#pragma unroll
      for (int mi = 0; mi < 2; ++mi) {
        int row = mi * 16 + (lane & 15);
        int slot = (kk * 4 + (lane >> 4)) ^ (row & 7);
        af[mi] = *(const f16x8*)&As[bufi][row][slot * 8];
      }
#pragma unroll
      for (int nj = 0; nj < 4; ++nj) {
        int row = wid * 64 + nj * 16 + (lane & 15);
        int slot = (kk * 4 + (lane >> 4)) ^ (row & 7);
        bfr[nj] = *(const f16x8*)&Bs[bufi][row][slot * 8];
      }
#pragma unroll
      for (int mi = 0; mi < 2; ++mi)
#pragma unroll
        for (int nj = 0; nj < 4; ++nj)
          acc[mi][nj] = __builtin_amdgcn_mfma_f32_16x16x32_f16(
              af[mi], bfr[nj], acc[mi][nj], 0, 0, 0);
    }
  };

  issueA(xlA, 0);
  if (tid < 224) T[tid] = cospif((float)tid / 112.0f);
  issueA(xlB, 1);
  __syncthreads();                    // T ready
  computeB(0, 0);

  asm volatile("s_waitcnt vmcnt(6)" ::: "memory");
  writeA(xlA, 0, 0);
  asm volatile("s_waitcnt lgkmcnt(0)" ::: "memory");
  __builtin_amdgcn_s_barrier();
  issueA(xlA, 2);
  computeB(1, 1);
  mfmaStep(0);
  __builtin_amdgcn_s_barrier();
  asm volatile("s_waitcnt vmcnt(6)" ::: "memory");
  writeA(xlB, 1, 1);
  asm volatile("s_waitcnt lgkmcnt(0)" ::: "memory");
  __builtin_amdgcn_s_barrier();
  issueA(xlB, 3);
  computeB(0, 2);
  mfmaStep(1);
  __builtin_amdgcn_s_barrier();
  asm volatile("s_waitcnt vmcnt(6)" ::: "memory");
  writeA(xlA, 2, 0);
  asm volatile("s_waitcnt lgkmcnt(0)" ::: "memory");
  __builtin_amdgcn_s_barrier();
  computeB(1, 3);
  mfmaStep(0);
  __builtin_amdgcn_s_barrier();
  asm volatile("s_waitcnt vmcnt(0)" ::: "memory");
  writeA(xlB, 3, 1);
  asm volatile("s_waitcnt lgkmcnt(0)" ::: "memory");
  __builtin_amdgcn_s_barrier();
  mfmaStep(1);

  int nbase = wid * 64;
#pragma unroll
  for (int mi = 0; mi < 2; ++mi) {
#pragma unroll
    for (int nj = 0; nj < 4; ++nj) {
      int c = nbase + nj * 16 + (lane & 15);
      if (c >= 226) continue;
      int m = m0 + mi * 16 + ((lane >> 4) << 2);
      int b = m / 224;
      int h = m - b * 224;
      int v = c, kb = h;
      if (c >= 113) { v = c - 113; kb = 224 + h; }
      size_t off = (size_t)(b * 128 + v) * 448 + kb;
      f32x4 y = acc[mi][nj];
      f16x4 hv;
#pragma unroll
      for (int r = 0; r < 4; ++r) hv[r] = (f16)y[r];
      *(f16x4*)&B2t[off] = hv;
    }
  }

  // tail: fill W2h row blockIdx.x; row 2u (re): cos|sin ; row 2u+1: -sin|cos
  {
    int r = blockIdx.x;
    int u = r >> 1;
    bool imrow = r & 1;
#pragma unroll
    for (int pass = 0; pass < 2; ++pass) {
      int k = pass * 256 + tid;
      if (k < 448) {
        bool kim = k >= 224;
        int kk = kim ? k - 224 : k;
        int m = (u * kk) % 224;
        float mf = (float)m / 112.0f;
        float c = cospif(mf), s = sinpif(mf);
        float val = imrow ? (kim ? c : -s) : (kim ? s : c);
        W2h[(size_t)r * 448 + k] = (f16)val;
      }
    }
  }
}

// ---- gemmB: F = W2h * B2t[b]^T; compiler-scheduled single-buffer core -----
// stats layout: [0]=gsum [1]=gsumsq [2+k]=s1 [10+k]=s2 [18+k]=max [26+k]=cnt
__global__ __launch_bounds__(256) void gemmB_kernel(const f16* __restrict__ W2h,
                                                    const f16* __restrict__ B2t,
                                                    float* __restrict__ stats) {
  __shared__ f16 As[64][64];        // 8 KB
  __shared__ f16 Bs[128][64];       // 16 KB
  int b = blockIdx.x;               // image (7 m-blocks land on one XCD: 64%8==0)
  int m0 = blockIdx.y * 64;
  int tid = threadIdx.x;
  int lane = tid & 63, wid = tid >> 6;
  int wr = wid >> 1, wc = wid & 1;
  const f16* Ap = W2h + (size_t)m0 * 448;
  const f16* Bp = B2t + (size_t)b * 128 * 448;

  int srow = lane >> 3;
  int sk8 = (lane & 7) ^ srow;

  f32x4 acc[2][4];
#pragma unroll
  for (int i = 0; i < 2; ++i)
#pragma unroll
    for (int j = 0; j < 4; ++j) acc[i][j] = (f32x4){0.f, 0.f, 0.f, 0.f};

#pragma unroll 1
  for (int t = 0; t < 7; ++t) {
    int k0 = t * 64;
#pragma unroll
    for (int ci = 0; ci < 6; ++ci) {
      int c = wid * 6 + ci;
      if (c < 8) {
        GLD16(Ap + (size_t)(c * 8 + srow) * 448 + k0 + sk8 * 8,
              &As[0][0] + c * 512);
      } else {
        int j = c - 8;
        GLD16(Bp + (size_t)(j * 8 + srow) * 448 + k0 + sk8 * 8,
              &Bs[0][0] + j * 512);
      }
    }
    __syncthreads();                // compiler inserts the right waitcnts
#pragma unroll
    for (int kk = 0; kk < 2; ++kk) {
      f16x8 af[2], bfr[4];
#pragma unroll
      for (int mi = 0; mi < 2; ++mi) {
        int row = wr * 32 + mi * 16 + (lane & 15);
        int slot = (kk * 4 + (lane >> 4)) ^ (row & 7);
        af[mi] = *(const f16x8*)&As[row][slot * 8];
      }
#pragma unroll
      for (int nj = 0; nj < 4; ++nj) {
        int row = wc * 64 + nj * 16 + (lane & 15);
        int slot = (kk * 4 + (lane >> 4)) ^ (row & 7);
        bfr[nj] = *(const f16x8*)&Bs[row][slot * 8];
      }
#pragma unroll
      for (int mi = 0; mi < 2; ++mi)
#pragma unroll
        for (int nj = 0; nj < 4; ++nj)
          acc[mi][nj] = __builtin_amdgcn_mfma_f32_16x16x32_f16(
              af[mi], bfr[nj], acc[mi][nj], 0, 0, 0);
    }
    __syncthreads();
  }

  // fused stats epilogue (verified R6-R13), plain atomics
  int rbase = m0 + wr * 32;
  const float step = (float)(158.39191898578665 / 8.0);
  float gsum = 0.f, gsq = 0.f;
  float s1[8] = {0}, s2[8] = {0}, cnt[8] = {0};
  float mx[8] = {0, 0, 0, 0, 0, 0, 0, 0};   // mag >= 0 always

#pragma unroll
  for (int mi = 0; mi < 2; ++mi) {
#pragma unroll
    for (int nj = 0; nj < 4; ++nj) {
      int n = wc * 64 + nj * 16 + (lane & 15);   // v, 0..127
      if (n >= 113) continue;
      float wgt = (n >= 1 && n <= 111) ? 2.f : 1.f;   // Hermitian mirror weight
      float dx2 = (float)(n * n);
      int rr = rbase + mi * 16 + ((lane >> 4) << 2);
      f32x4 f = acc[mi][nj];
#pragma unroll
      for (int p = 0; p < 2; ++p) {
        int u = (rr >> 1) + p;
        float re = f[2 * p], im = f[2 * p + 1];
        float mv = log1pf(sqrtf(re * re + im * im));
        int a = (u <= 111) ? u : 224 - u;
        float r = sqrtf((float)(a * a) + dx2);
        int bd = 255;
#pragma unroll
        for (int k = 0; k < 8; k++) {
          float lo = step * (float)k;
          float hi = step * (float)(k + 1);
          if (r >= lo && r < hi) bd = k;
        }
        float wm = wgt * mv;
        gsum += wm;
        gsq += wm * mv;
#pragma unroll
        for (int k = 0; k < 8; k++) {
          bool m = (bd == k);
          s1[k] += m ? wm : 0.f;
          s2[k] += m ? wm * mv : 0.f;
          cnt[k] += m ? wgt : 0.f;
          mx[k] = m ? fmaxf(mx[k], mv) : mx[k];
        }
      }
    }
  }

  float vals[34];
  vals[0] = gsum; vals[1] = gsq;
#pragma unroll
  for (int k = 0; k < 8; k++) {
    vals[2 + k] = s1[k]; vals[10 + k] = s2[k]; vals[18 + k] = mx[k]; vals[26 + k] = cnt[k];
  }
#pragma unroll
  for (int i = 0; i < 34; i++) {
    float v = vals[i];
    const bool isMax = (i >= 18 && i < 26);
#pragma unroll
    for (int off = 32; off > 0; off >>= 1) {
      float o = __shfl_down(v, off);
      v = isMax ? fmaxf(v, o) : (v + o);
    }
    vals[i] = v;
  }
  float* red = (float*)&As[0][0];   // reuse LDS (all reads done)
  if ((tid & 63) == 0) {
#pragma unroll
    for (int i = 0; i < 34; i++) red[wid * 34 + i] = vals[i];
  }
  __syncthreads();
  if (tid < 34) {
    bool isMax = (tid >= 18 && tid < 26);
    float v = red[tid];
#pragma unroll
    for (int ww = 1; ww < 4; ww++) {
      float o = red[ww * 34 + tid];
      v = isMax ? fmaxf(v, o) : (v + o);
    }
    if (isMax)
      atomicMax((u32*)&stats[b * 34 + tid], __float_as_uint(v));  // v >= 0
    else
      atomicAdd(&stats[b * 34 + tid], v);
  }
}

// ---- MLP: 256 blocks, 2 bands each, shared-j W2m loop (R9-proven) ---------
__global__ __launch_bounds__(256) void mlp_kernel(const float* __restrict__ stats,
                                                  const float* __restrict__ W1,
                                                  const float* __restrict__ b1,
                                                  const float* __restrict__ gamma,
                                                  const float* __restrict__ beta,
                                                  const float* __restrict__ W2m,
                                                  const float* __restrict__ b2,
                                                  float* __restrict__ out) {
  int blk = blockIdx.x;
  int b = blk >> 2;
  int k0 = (blk & 3) * 2;
  int e = threadIdx.x;
  int lane = e & 63, wave = e >> 6;

  __shared__ float st[34];
  if (e < 34) st[e] = stats[b * 34 + e];
  __syncthreads();

  const float N = (float)NPIX;
  float mu = st[0] / N;
  float varg = fmaxf(st[1] - N * mu * mu, 0.0f) / (N - 1.0f);
  float sd = sqrtf(varg) + 1e-6f;

  float g_e = gamma[e], bt_e = beta[e], b1_e = b1[e];
  float w1a = W1[e], w1b = W1[EDIM + e], w1c = W1[2 * EDIM + e];

  float h[2];
#pragma unroll
  for (int q = 0; q < 2; ++q) {
    int k = k0 + q;
    float s1r = st[2 + k], s2r = st[10 + k], mxr = st[18 + k], cntk = st[26 + k];
    float ms = cntk + 1e-6f;
    float s1n = (s1r - mu * cntk) / sd;
    float s2n = (s2r - 2.0f * mu * s1r + mu * mu * cntk) / (sd * sd);
    float mean_k = s1n / ms;
    float var_num = s2n - 2.0f * mean_k * s1n + mean_k * mean_k * cntk;
    float std_k = sqrtf(var_num / ms + 1e-6f);
    float max_k = (mxr - mu) / sd;
    h[q] = mean_k * w1a + std_k * w1b + max_k * w1c + b1_e;
  }

  float v4[4] = {h[0], h[0] * h[0], h[1], h[1] * h[1]};
#pragma unroll
  for (int i = 0; i < 4; ++i) {
#pragma unroll
    for (int off = 32; off > 0; off >>= 1) v4[i] += __shfl_down(v4[i], off);
  }
  __shared__ float red[4][4];
  __shared__ float mm[4];
  if (lane == 0) {
#pragma unroll
    for (int i = 0; i < 4; ++i) red[wave][i] = v4[i];
  }
  __syncthreads();
  if (e == 0) {
#pragma unroll
    for (int i = 0; i < 4; ++i) {
      float t = red[0][i] + red[1][i] + red[2][i] + red[3][i];
      red[0][i] = t;
    }
    float hm0 = red[0][0] / 256.0f, hm1 = red[0][2] / 256.0f;
    mm[0] = hm0;
    mm[1] = fmaxf(red[0][1] / 256.0f - hm0 * hm0, 0.0f);
    mm[2] = hm1;
    mm[3] = fmaxf(red[0][3] / 256.0f - hm1 * hm1, 0.0f);
  }
  __syncthreads();

  __shared__ float hsT[EDIM][2];
#pragma unroll
  for (int q = 0; q < 2; ++q) {
    float hn = (h[q] - mm[2 * q]) / sqrtf(mm[2 * q + 1] + 1e-5f) * g_e + bt_e;
    hsT[e][q] = fmaxf(hn, 0.0f);
  }
  __syncthreads();

  float a0 = b2[e], a1 = a0;
#pragma unroll 8
  for (int j = 0; j < EDIM; j++) {
    float w = W2m[j * EDIM + e];
    float2 hp = *(const float2*)&hsT[j][0];
    a0 += hp.x * w;
    a1 += hp.y * w;
  }
  out[(size_t)(b * 8 + k0) * EDIM + e] = a0;
  out[(size_t)(b * 8 + k0 + 1) * EDIM + e] = a1;
}

// ---- launch ---------------------------------------------------------------
extern "C" void kernel_launch(void* const* d_in, const int* in_sizes, int n_in,
                              void* d_out, int out_size, void* d_ws, size_t ws_size,
                              hipStream_t stream) {
  const float* x     = (const float*)d_in[0];
  const float* W1    = (const float*)d_in[1];
  const float* b1    = (const float*)d_in[2];
  const float* gamma = (const float*)d_in[3];
  const float* beta  = (const float*)d_in[4];
  const float* W2m   = (const float*)d_in[5];
  const float* b2    = (const float*)d_in[6];
  float* out = (float*)d_out;

  char* W = (char*)d_ws;
  f16* B2t = (f16*)W;                       // [64][128][448] = 7,340,032 B
  float* stats = (float*)(W + 7340032);     // 64*34 f32 = 8,704 B
  f16* W2h = (f16*)(W + 7340032 + 8704);    // [448][448] = 401,408 B

  gemmA_kernel<<<dim3(448), dim3(256), 0, stream>>>(x, B2t, W2h, (u32*)stats);
  gemmB_kernel<<<dim3(BATCH, 7), dim3(256), 0, stream>>>(W2h, B2t, stats);
  mlp_kernel<<<dim3(256), dim3(256), 0, stream>>>(stats, W1, b1, gamma, beta, W2m, b2, out);
}

// Round 15
// 50.935 us; speedup vs baseline: 1.0060x; 1.0060x over previous
//
#include <hip/hip_runtime.h>
#include <math.h>

#define IMG 224
#define NPIX 50176
#define BATCH 64
#define EDIM 256

typedef _Float16 f16;
typedef __attribute__((ext_vector_type(8))) _Float16 f16x8;
typedef __attribute__((ext_vector_type(4))) _Float16 f16x4;
typedef __attribute__((ext_vector_type(4))) float f32x4;
typedef unsigned int u32;

// gemmA: 32x256 tile, 448 blocks, A=gray(x) reg-staged 2-deep prefetch,
//   B=B1 Chebyshev-recurrence in LDS. HBM-FLOOR ~6.5us — frozen. Zero GLD16.
//   Tail: fills one W2h row per block; block 0 zeroes stats.
// gemmB: R15 ABLATION — R14's single-buffer compiler-scheduled core with the
//   ONLY change: staging via registers + ds_write_b128 instead of
//   global_load_lds. (R12/R13/R14: three different schedules, identical
//   ~38us -> schedule-independent; GLD16 is the lone element shared by all
//   slow gemmBs and absent from the fast gemmA.) LDS bytes written are
//   bit-identical to the GLD16 layout (lane l -> chunk + l*16, src slot sk8).
// mlp: R9-proven paired version.

// ---- gemmA: Y = gray(x) * B1^T -> fp16 B2t; fills W2h; zeroes stats -------
__global__ __launch_bounds__(256) void gemmA_kernel(const float* __restrict__ x,
                                                    f16* __restrict__ B2t,
                                                    f16* __restrict__ W2h,
                                                    u32* __restrict__ statsz) {
  __shared__ float T[224];
  __shared__ f16 As[2][32][64];     // 8 KB
  __shared__ f16 Bs[2][256][64];    // 64 KB
  int m0 = blockIdx.x * 32;
  int tid = threadIdx.x;
  int lane = tid & 63, wid = tid >> 6;

  if (blockIdx.x == 0) {            // stats (2176 f32)
#pragma unroll
    for (int i = 0; i < 9; ++i) {
      int idx = i * 256 + tid;
      if (idx < 2176) statsz[idx] = 0u;
    }
  }

  int arow = tid >> 3;
  int aseg = tid & 7;
  int am = m0 + arow;
  int ab = am / 224, ah = am - ab * 224;
  const float* px = x + (size_t)ab * 3 * NPIX + ah * IMG;
  int s0 = aseg ^ (arow & 7);       // swizzled 16B slot (involution)

  f32x4 xlA[3][2], xlB[3][2];
  f32x4 acc[2][4];
#pragma unroll
  for (int i = 0; i < 2; ++i)
#pragma unroll
    for (int j = 0; j < 4; ++j) acc[i][j] = (f32x4){0.f, 0.f, 0.f, 0.f};

  auto issueA = [&](f32x4 (&xl)[3][2], int t) {
    int kb = t * 64 + aseg * 8;
    if (kb < 224) {
#pragma unroll
      for (int c = 0; c < 3; ++c) {
        xl[c][0] = *(const f32x4*)(px + c * NPIX + kb);
        xl[c][1] = *(const f32x4*)(px + c * NPIX + kb + 4);
      }
    }
  };
  auto writeA = [&](f32x4 (&xl)[3][2], int t, int bufi) {
    int kb = t * 64 + aseg * 8;
    f16x8 h0;
    if (kb < 224) {
#pragma unroll
      for (int j = 0; j < 8; ++j) {
        int q = j >> 2, r = j & 3;
        h0[j] = (f16)((xl[0][q][r] + xl[1][q][r] + xl[2][q][r]) * (1.0f / 3.0f));
      }
    } else {
#pragma unroll
      for (int j = 0; j < 8; ++j) h0[j] = (f16)0.f;
    }
    *(f16x8*)&As[bufi][arow][s0 * 8] = h0;
  };
  auto computeB = [&](int bufi, int t) {
    int row = tid;
    int v = (row < 113) ? row : row - 113;
    u32 off = (row < 113) ? 0u : 56u;
    u32 idx0 = ((u32)(t * 64) * (u32)v + off) % 224u;
    u32 idxm = (idx0 >= (u32)v) ? idx0 - (u32)v : idx0 + 224u - (u32)v;
    float cur = T[idx0];
    float prev = T[idxm];
    float k2c = 2.0f * T[v];
#pragma unroll
    for (int g = 0; g < 8; ++g) {
      f16x8 hv;
#pragma unroll
      for (int j = 0; j < 8; ++j) {
        hv[j] = (f16)cur;
        float nxt = __builtin_fmaf(k2c, cur, -prev);
        prev = cur; cur = nxt;
      }
      *(f16x8*)&Bs[bufi][row][(g ^ (row & 7)) * 8] = hv;
    }
  };
  auto mfmaStep = [&](int bufi) {
#pragma unroll
    for (int kk = 0; kk < 2; ++kk) {
      f16x8 af[2], bfr[4];
#pragma unroll
      for (int mi = 0; mi < 2; ++mi) {
        int row = mi * 16 + (lane & 15);
        int slot = (kk * 4 + (lane >> 4)) ^ (row & 7);
        af[mi] = *(const f16x8*)&As[bufi][row][slot * 8];
      }
#pragma unroll
      for (int nj = 0; nj < 4; ++nj) {
        int row = wid * 64 + nj * 16 + (lane & 15);
        int slot = (kk * 4 + (lane >> 4)) ^ (row & 7);
        bfr[nj] = *(const f16x8*)&Bs[bufi][row][slot * 8];
      }
#pragma unroll
      for (int mi = 0; mi < 2; ++mi)
#pragma unroll
        for (int nj = 0; nj < 4; ++nj)
          acc[mi][nj] = __builtin_amdgcn_mfma_f32_16x16x32_f16(
              af[mi], bfr[nj], acc[mi][nj], 0, 0, 0);
    }
  };

  issueA(xlA, 0);
  if (tid < 224) T[tid] = cospif((float)tid / 112.0f);
  issueA(xlB, 1);
  __syncthreads();                    // T ready
  computeB(0, 0);

  asm volatile("s_waitcnt vmcnt(6)" ::: "memory");
  writeA(xlA, 0, 0);
  asm volatile("s_waitcnt lgkmcnt(0)" ::: "memory");
  __builtin_amdgcn_s_barrier();
  issueA(xlA, 2);
  computeB(1, 1);
  mfmaStep(0);
  __builtin_amdgcn_s_barrier();
  asm volatile("s_waitcnt vmcnt(6)" ::: "memory");
  writeA(xlB, 1, 1);
  asm volatile("s_waitcnt lgkmcnt(0)" ::: "memory");
  __builtin_amdgcn_s_barrier();
  issueA(xlB, 3);
  computeB(0, 2);
  mfmaStep(1);
  __builtin_amdgcn_s_barrier();
  asm volatile("s_waitcnt vmcnt(6)" ::: "memory");
  writeA(xlA, 2, 0);
  asm volatile("s_waitcnt lgkmcnt(0)" ::: "memory");
  __builtin_amdgcn_s_barrier();
  computeB(1, 3);
  mfmaStep(0);
  __builtin_amdgcn_s_barrier();
  asm volatile("s_waitcnt vmcnt(0)" ::: "memory");
  writeA(xlB, 3, 1);
  asm volatile("s_waitcnt lgkmcnt(0)" ::: "memory");
  __builtin_amdgcn_s_barrier();
  mfmaStep(1);

  int nbase = wid * 64;
#pragma unroll
  for (int mi = 0; mi < 2; ++mi) {
#pragma unroll
    for (int nj = 0; nj < 4; ++nj) {
      int c = nbase + nj * 16 + (lane & 15);
      if (c >= 226) continue;
      int m = m0 + mi * 16 + ((lane >> 4) << 2);
      int b = m / 224;
      int h = m - b * 224;
      int v = c, kb = h;
      if (c >= 113) { v = c - 113; kb = 224 + h; }
      size_t off = (size_t)(b * 128 + v) * 448 + kb;
      f32x4 y = acc[mi][nj];
      f16x4 hv;
#pragma unroll
      for (int r = 0; r < 4; ++r) hv[r] = (f16)y[r];
      *(f16x4*)&B2t[off] = hv;
    }
  }

  // tail: fill W2h row blockIdx.x; row 2u (re): cos|sin ; row 2u+1: -sin|cos
  {
    int r = blockIdx.x;
    int u = r >> 1;
    bool imrow = r & 1;
#pragma unroll
    for (int pass = 0; pass < 2; ++pass) {
      int k = pass * 256 + tid;
      if (k < 448) {
        bool kim = k >= 224;
        int kk = kim ? k - 224 : k;
        int m = (u * kk) % 224;
        float mf = (float)m / 112.0f;
        float c = cospif(mf), s = sinpif(mf);
        float val = imrow ? (kim ? c : -s) : (kim ? s : c);
        W2h[(size_t)r * 448 + k] = (f16)val;
      }
    }
  }
}

// ---- gemmB: F = W2h * B2t[b]^T; REGISTER-staged (no global_load_lds) ------
// stats layout: [0]=gsum [1]=gsumsq [2+k]=s1 [10+k]=s2 [18+k]=max [26+k]=cnt
__global__ __launch_bounds__(256) void gemmB_kernel(const f16* __restrict__ W2h,
                                                    const f16* __restrict__ B2t,
                                                    float* __restrict__ stats) {
  __shared__ f16 As[64][64];        // 8 KB
  __shared__ f16 Bs[128][64];       // 16 KB
  int b = blockIdx.x;               // image
  int m0 = blockIdx.y * 64;
  int tid = threadIdx.x;
  int lane = tid & 63, wid = tid >> 6;
  int wr = wid >> 1, wc = wid & 1;
  const f16* Ap = W2h + (size_t)m0 * 448;
  const f16* Bp = B2t + (size_t)b * 128 * 448;

  int srow = lane >> 3;
  int sk8 = (lane & 7) ^ srow;

  f32x4 acc[2][4];
#pragma unroll
  for (int i = 0; i < 2; ++i)
#pragma unroll
    for (int j = 0; j < 4; ++j) acc[i][j] = (f32x4){0.f, 0.f, 0.f, 0.f};

  // Reg-staging: same LDS bytes as the GLD16 layout (lane l -> chunk + l*16B,
  // global source slot sk8), so the swizzled MFMA read side is unchanged.
  auto stage_load = [&](f16x8 (&tmp)[6], int t) {
    int k0 = t * 64;
#pragma unroll
    for (int ci = 0; ci < 6; ++ci) {
      int c = wid * 6 + ci;
      const f16* src = (c < 8)
          ? Ap + (size_t)(c * 8 + srow) * 448 + k0 + sk8 * 8
          : Bp + (size_t)((c - 8) * 8 + srow) * 448 + k0 + sk8 * 8;
      tmp[ci] = *(const f16x8*)src;
    }
  };
  auto stage_write = [&](f16x8 (&tmp)[6]) {
#pragma unroll
    for (int ci = 0; ci < 6; ++ci) {
      int c = wid * 6 + ci;
      f16* dst = (c < 8) ? (&As[0][0] + c * 512 + lane * 8)
                         : (&Bs[0][0] + (c - 8) * 512 + lane * 8);
      *(f16x8*)dst = tmp[ci];
    }
  };
  auto mfmaStep = [&]() {
#pragma unroll
    for (int kk = 0; kk < 2; ++kk) {
      f16x8 af[2], bfr[4];
#pragma unroll
      for (int mi = 0; mi < 2; ++mi) {
        int row = wr * 32 + mi * 16 + (lane & 15);
        int slot = (kk * 4 + (lane >> 4)) ^ (row & 7);
        af[mi] = *(const f16x8*)&As[row][slot * 8];
      }
#pragma unroll
      for (int nj = 0; nj < 4; ++nj) {
        int row = wc * 64 + nj * 16 + (lane & 15);
        int slot = (kk * 4 + (lane >> 4)) ^ (row & 7);
        bfr[nj] = *(const f16x8*)&Bs[row][slot * 8];
      }
#pragma unroll
      for (int mi = 0; mi < 2; ++mi)
#pragma unroll
        for (int nj = 0; nj < 4; ++nj)
          acc[mi][nj] = __builtin_amdgcn_mfma_f32_16x16x32_f16(
              af[mi], bfr[nj], acc[mi][nj], 0, 0, 0);
    }
  };
  auto step = [&](f16x8 (&curT)[6], f16x8 (&nxtT)[6], int t, bool last) {
    stage_write(curT);
    __syncthreads();                 // tile t staged
    if (!last) stage_load(nxtT, t + 1);   // overlap t+1 loads with MFMAs
    mfmaStep();
    __syncthreads();                 // reads done, LDS free for t+1
  };

  f16x8 tA[6], tB[6];
  stage_load(tA, 0);
  step(tA, tB, 0, false);
  step(tB, tA, 1, false);
  step(tA, tB, 2, false);
  step(tB, tA, 3, false);
  step(tA, tB, 4, false);
  step(tB, tA, 5, false);
  step(tA, tA, 6, true);

  // fused stats epilogue (verified R6-R14), plain atomics
  int rbase = m0 + wr * 32;
  const float step_ = (float)(158.39191898578665 / 8.0);
  float gsum = 0.f, gsq = 0.f;
  float s1[8] = {0}, s2[8] = {0}, cnt[8] = {0};
  float mx[8] = {0, 0, 0, 0, 0, 0, 0, 0};   // mag >= 0 always

#pragma unroll
  for (int mi = 0; mi < 2; ++mi) {
#pragma unroll
    for (int nj = 0; nj < 4; ++nj) {
      int n = wc * 64 + nj * 16 + (lane & 15);   // v, 0..127
      if (n >= 113) continue;
      float wgt = (n >= 1 && n <= 111) ? 2.f : 1.f;   // Hermitian mirror weight
      float dx2 = (float)(n * n);
      int rr = rbase + mi * 16 + ((lane >> 4) << 2);
      f32x4 f = acc[mi][nj];
#pragma unroll
      for (int p = 0; p < 2; ++p) {
        int u = (rr >> 1) + p;
        float re = f[2 * p], im = f[2 * p + 1];
        float mv = log1pf(sqrtf(re * re + im * im));
        int a = (u <= 111) ? u : 224 - u;
        float r = sqrtf((float)(a * a) + dx2);
        int bd = 255;
#pragma unroll
        for (int k = 0; k < 8; k++) {
          float lo = step_ * (float)k;
          float hi = step_ * (float)(k + 1);
          if (r >= lo && r < hi) bd = k;
        }
        float wm = wgt * mv;
        gsum += wm;
        gsq += wm * mv;
#pragma unroll
        for (int k = 0; k < 8; k++) {
          bool m = (bd == k);
          s1[k] += m ? wm : 0.f;
          s2[k] += m ? wm * mv : 0.f;
          cnt[k] += m ? wgt : 0.f;
          mx[k] = m ? fmaxf(mx[k], mv) : mx[k];
        }
      }
    }
  }

  float vals[34];
  vals[0] = gsum; vals[1] = gsq;
#pragma unroll
  for (int k = 0; k < 8; k++) {
    vals[2 + k] = s1[k]; vals[10 + k] = s2[k]; vals[18 + k] = mx[k]; vals[26 + k] = cnt[k];
  }
#pragma unroll
  for (int i = 0; i < 34; i++) {
    float v = vals[i];
    const bool isMax = (i >= 18 && i < 26);
#pragma unroll
    for (int off = 32; off > 0; off >>= 1) {
      float o = __shfl_down(v, off);
      v = isMax ? fmaxf(v, o) : (v + o);
    }
    vals[i] = v;
  }
  float* red = (float*)&As[0][0];   // reuse LDS (all reads done)
  if ((tid & 63) == 0) {
#pragma unroll
    for (int i = 0; i < 34; i++) red[wid * 34 + i] = vals[i];
  }
  __syncthreads();
  if (tid < 34) {
    bool isMax = (tid >= 18 && tid < 26);
    float v = red[tid];
#pragma unroll
    for (int ww = 1; ww < 4; ww++) {
      float o = red[ww * 34 + tid];
      v = isMax ? fmaxf(v, o) : (v + o);
    }
    if (isMax)
      atomicMax((u32*)&stats[b * 34 + tid], __float_as_uint(v));  // v >= 0
    else
      atomicAdd(&stats[b * 34 + tid], v);
  }
}

// ---- MLP: 256 blocks, 2 bands each, shared-j W2m loop (R9-proven) ---------
__global__ __launch_bounds__(256) void mlp_kernel(const float* __restrict__ stats,
                                                  const float* __restrict__ W1,
                                                  const float* __restrict__ b1,
                                                  const float* __restrict__ gamma,
                                                  const float* __restrict__ beta,
                                                  const float* __restrict__ W2m,
                                                  const float* __restrict__ b2,
                                                  float* __restrict__ out) {
  int blk = blockIdx.x;
  int b = blk >> 2;
  int k0 = (blk & 3) * 2;
  int e = threadIdx.x;
  int lane = e & 63, wave = e >> 6;

  __shared__ float st[34];
  if (e < 34) st[e] = stats[b * 34 + e];
  __syncthreads();

  const float N = (float)NPIX;
  float mu = st[0] / N;
  float varg = fmaxf(st[1] - N * mu * mu, 0.0f) / (N - 1.0f);
  float sd = sqrtf(varg) + 1e-6f;

  float g_e = gamma[e], bt_e = beta[e], b1_e = b1[e];
  float w1a = W1[e], w1b = W1[EDIM + e], w1c = W1[2 * EDIM + e];

  float h[2];
#pragma unroll
  for (int q = 0; q < 2; ++q) {
    int k = k0 + q;
    float s1r = st[2 + k], s2r = st[10 + k], mxr = st[18 + k], cntk = st[26 + k];
    float ms = cntk + 1e-6f;
    float s1n = (s1r - mu * cntk) / sd;
    float s2n = (s2r - 2.0f * mu * s1r + mu * mu * cntk) / (sd * sd);
    float mean_k = s1n / ms;
    float var_num = s2n - 2.0f * mean_k * s1n + mean_k * mean_k * cntk;
    float std_k = sqrtf(var_num / ms + 1e-6f);
    float max_k = (mxr - mu) / sd;
    h[q] = mean_k * w1a + std_k * w1b + max_k * w1c + b1_e;
  }

  float v4[4] = {h[0], h[0] * h[0], h[1], h[1] * h[1]};
#pragma unroll
  for (int i = 0; i < 4; ++i) {
#pragma unroll
    for (int off = 32; off > 0; off >>= 1) v4[i] += __shfl_down(v4[i], off);
  }
  __shared__ float red[4][4];
  __shared__ float mm[4];
  if (lane == 0) {
#pragma unroll
    for (int i = 0; i < 4; ++i) red[wave][i] = v4[i];
  }
  __syncthreads();
  if (e == 0) {
#pragma unroll
    for (int i = 0; i < 4; ++i) {
      float t = red[0][i] + red[1][i] + red[2][i] + red[3][i];
      red[0][i] = t;
    }
    float hm0 = red[0][0] / 256.0f, hm1 = red[0][2] / 256.0f;
    mm[0] = hm0;
    mm[1] = fmaxf(red[0][1] / 256.0f - hm0 * hm0, 0.0f);
    mm[2] = hm1;
    mm[3] = fmaxf(red[0][3] / 256.0f - hm1 * hm1, 0.0f);
  }
  __syncthreads();

  __shared__ float hsT[EDIM][2];
#pragma unroll
  for (int q = 0; q < 2; ++q) {
    float hn = (h[q] - mm[2 * q]) / sqrtf(mm[2 * q + 1] + 1e-5f) * g_e + bt_e;
    hsT[e][q] = fmaxf(hn, 0.0f);
  }
  __syncthreads();

  float a0 = b2[e], a1 = a0;
#pragma unroll 8
  for (int j = 0; j < EDIM; j++) {
    float w = W2m[j * EDIM + e];
    float2 hp = *(const float2*)&hsT[j][0];
    a0 += hp.x * w;
    a1 += hp.y * w;
  }
  out[(size_t)(b * 8 + k0) * EDIM + e] = a0;
  out[(size_t)(b * 8 + k0 + 1) * EDIM + e] = a1;
}

// ---- launch ---------------------------------------------------------------
extern "C" void kernel_launch(void* const* d_in, const int* in_sizes, int n_in,
                              void* d_out, int out_size, void* d_ws, size_t ws_size,
                              hipStream_t stream) {
  const float* x     = (const float*)d_in[0];
  const float* W1    = (const float*)d_in[1];
  const float* b1    = (const float*)d_in[2];
  const float* gamma = (const float*)d_in[3];
  const float* beta  = (const float*)d_in[4];
  const float* W2m   = (const float*)d_in[5];
  const float* b2    = (const float*)d_in[6];
  float* out = (float*)d_out;

  char* W = (char*)d_ws;
  f16* B2t = (f16*)W;                       // [64][128][448] = 7,340,032 B
  float* stats = (float*)(W + 7340032);     // 64*34 f32 = 8,704 B
  f16* W2h = (f16*)(W + 7340032 + 8704);    // [448][448] = 401,408 B

  gemmA_kernel<<<dim3(448), dim3(256), 0, stream>>>(x, B2t, W2h, (u32*)stats);
  gemmB_kernel<<<dim3(BATCH, 7), dim3(256), 0, stream>>>(W2h, B2t, stats);
  mlp_kernel<<<dim3(256), dim3(256), 0, stream>>>(stats, W1, b1, gamma, beta, W2m, b2, out);
}